// Round 6
// baseline (542.701 us; speedup 1.0000x reference)
//
#include <hip/hip_runtime.h>
#include <math.h>

// Problem constants (B, C, H, W) = (4, 128, 192, 192)
#define BB 4
#define CC 128
#define HH 192
#define WW 192
#define HWSZ (HH * WW)          // 36864
#define NPIX (BB * HWSZ)        // 147456
#define PR 194                  // padded rows (h = -1..192)
#define PC 208                  // padded col units (16B units per row; 128B-aligned rows)
// col unit for pixel w is (8 + w); zero borders at units 7 and 200.

typedef __attribute__((ext_vector_type(8))) short short8;
typedef __attribute__((ext_vector_type(4))) short short4v;
typedef __attribute__((ext_vector_type(4))) float float4v;

// fp32 -> bf16, round-to-nearest-even
__device__ __forceinline__ short f2bf(float f) {
    unsigned u = __float_as_uint(f);
    u += 0x7FFF + ((u >> 16) & 1);
    return (short)(u >> 16);
}
__device__ __forceinline__ float bf2f(short s) {
    return __uint_as_float(((unsigned)(unsigned short)s) << 16);
}

// ---------------------------------------------------------------------------
// Weight prep:  w[co][cin][ky][kx] fp32  ->  wp[ck][tap][co][ci] bf16
// ---------------------------------------------------------------------------
__global__ void prep_w_kernel(const float* __restrict__ w,
                              short* __restrict__ wp,
                              int CIN, int COUT, int total) {
    int idx = blockIdx.x * blockDim.x + threadIdx.x;
    if (idx >= total) return;
    int ci  = idx & 31;
    int rem = idx >> 5;
    int co  = rem % COUT;
    int r2  = rem / COUT;
    int tap = r2 % 9;
    int ck  = r2 / 9;
    int cin = ck * 32 + ci;
    wp[idx] = f2bf(w[(co * CIN + cin) * 9 + tap]);
}

// ---------------------------------------------------------------------------
// Zero the borders of the three padded bf16 activation buffers.
// Per (buf, b*cg) plane: rows 0 & 193 full (208 units) + units 7,200 of rows
// 1..192  -> 800 units each.
// ---------------------------------------------------------------------------
__global__ void zero_pads_kernel(short* __restrict__ p0,
                                 short* __restrict__ p1,
                                 short* __restrict__ p2) {
    int idx = blockIdx.x * blockDim.x + threadIdx.x;
    if (idx >= 3 * 64 * 800) return;
    int e   = idx % 800;
    int bc  = (idx / 800) % 64;
    int buf = idx / (800 * 64);
    short* base = (buf == 0) ? p0 : (buf == 1) ? p1 : p2;
    int row, col;
    if (e < 208)      { row = 0;   col = e; }
    else if (e < 416) { row = 193; col = e - 208; }
    else { int e2 = e - 416; row = 1 + (e2 >> 1); col = (e2 & 1) ? 200 : 7; }
    short8 z = {0, 0, 0, 0, 0, 0, 0, 0};
    *(short8*)&base[(((size_t)bc * PR + row) * PC + col) * 8] = z;
}

// ---------------------------------------------------------------------------
// x fp32 NCHW -> padded bf16 8c-blocked [b][cg][h+1][8+w][8]
// ---------------------------------------------------------------------------
__global__ void x_prep_kernel(const float* __restrict__ x,
                              short* __restrict__ xp) {
    int idx = blockIdx.x * blockDim.x + threadIdx.x;
    if (idx >= BB * 16 * HWSZ) return;
    int w  = idx % WW;
    int h  = (idx / WW) % HH;
    int cg = (idx / HWSZ) % 16;
    int b  = idx / (HWSZ * 16);
    const float* p = x + ((size_t)(b * CC + cg * 8) * HH + h) * WW + w;
    short8 pk;
#pragma unroll
    for (int j = 0; j < 8; ++j) pk[j] = f2bf(p[(size_t)j * HWSZ]);
    *(short8*)&xp[((((size_t)b * 16 + cg) * PR + h + 1) * PC + (8 + w)) * 8] = pk;
}

// ---------------------------------------------------------------------------
// Implicit-GEMM 3x3 conv, bf16 MFMA 16x16x32, fp32 accumulate. Barrier-free.
// WAVES_M = 1: every wave covers ALL couts (WM = COUT/16) -> the A (weight)
// stream is identical across the block's 4 waves and is L1-broadcast; B
// (activations) read direct from the padded 8c-blocked global buffer.
// Per-wave: WM x WN acc tiles, A+B ping-pong prefetched one K-step ahead.
// ---------------------------------------------------------------------------
template <int CIN, int COUT, int WM, int WN, bool RELU, bool OUT_F32>
__global__ __launch_bounds__(256, 2)
void conv3x3_direct(const short* __restrict__ in,
                    const short* __restrict__ wp,   // [ck][tap][co][32ci] bf16
                    const float* __restrict__ bias,
                    void* __restrict__ outv) {
    constexpr int CKN   = CIN / 32;
    constexpr int CG_IN = CIN / 8;
    constexpr int CGO   = COUT / 8;
    constexpr int KT    = CKN * 9;
    static_assert(WM * 16 == COUT, "M tiling");
    static_assert(4 * WN * 16 == 192, "N tiling");

    const int tid  = threadIdx.x;
    const int h    = blockIdx.x;
    const int b    = blockIdx.y;
    const int lane = tid & 63;
    const int wv   = tid >> 6;               // wave = N-position 0..3
    const int px0  = wv * WN * 16;
    const int ln15 = lane & 15;
    const int lg   = lane >> 4;              // k-subgroup 0..3 (8 cins each)

    float4v acc[WM][WN];
#pragma unroll
    for (int mi = 0; mi < WM; ++mi)
#pragma unroll
        for (int ni = 0; ni < WN; ++ni)
            acc[mi][ni] = (float4v){0.f, 0.f, 0.f, 0.f};

    short8 Ab[2][WM], Bb[2][WN];

    auto loadA = [&](int kt, short8* dst) {
        const int ck = kt / 9, tap = kt % 9;
#pragma unroll
        for (int mi = 0; mi < WM; ++mi) {
            int co = mi * 16 + ln15;
            dst[mi] = *(const short8*)
                &wp[(((size_t)(ck * 9 + tap)) * COUT + co) * 32 + lg * 8];
        }
    };
    auto loadB = [&](int kt, short8* dst) {
        const int ck = kt / 9, tap = kt % 9;
        const int dy = tap / 3, dx = tap % 3;
#pragma unroll
        for (int ni = 0; ni < WN; ++ni) {
            int colu = 7 + px0 + ni * 16 + ln15 + dx;   // 8 + (px + dx - 1)
            dst[ni] = *(const short8*)
                &in[((((size_t)b * CG_IN + ck * 4 + lg) * PR + (h + dy)) * PC + colu) * 8];
        }
    };

    loadA(0, Ab[0]);
    loadB(0, Bb[0]);
#pragma unroll
    for (int kt = 0; kt < KT; ++kt) {
        if (kt + 1 < KT) {
            loadA(kt + 1, Ab[(kt + 1) & 1]);
            loadB(kt + 1, Bb[(kt + 1) & 1]);
        }
#pragma unroll
        for (int mi = 0; mi < WM; ++mi)
#pragma unroll
            for (int ni = 0; ni < WN; ++ni)
                acc[mi][ni] = __builtin_amdgcn_mfma_f32_16x16x32_bf16(
                    Ab[kt & 1][mi], Bb[kt & 1][ni], acc[mi][ni], 0, 0, 0);
    }

    // ---- epilogue: C layout col=lane&15 (pixel), row=lg*4+reg (cout) ----
    if (OUT_F32) {
        float* out = (float*)outv;
#pragma unroll
        for (int mi = 0; mi < WM; ++mi) {
            int co0 = mi * 16 + lg * 4;
#pragma unroll
            for (int r = 0; r < 4; ++r) {
                int co = co0 + r;
                float bv = bias[co];
#pragma unroll
                for (int ni = 0; ni < WN; ++ni) {
                    int wcol = px0 + ni * 16 + ln15;
                    float v = acc[mi][ni][r] + bv;
                    if (RELU) v = fmaxf(v, 0.f);
                    out[((size_t)(b * COUT + co) * HH + h) * WW + wcol] = v;
                }
            }
        }
    } else {
        short* out = (short*)outv;
#pragma unroll
        for (int mi = 0; mi < WM; ++mi) {
            int co0 = mi * 16 + lg * 4;          // 4 consecutive couts
            int cg  = co0 >> 3;
            int sub = co0 & 7;                   // 0 or 4
#pragma unroll
            for (int ni = 0; ni < WN; ++ni) {
                int wcol = px0 + ni * 16 + ln15;
                short4v pk;
#pragma unroll
                for (int r = 0; r < 4; ++r) {
                    float v = acc[mi][ni][r] + bias[co0 + r];
                    if (RELU) v = fmaxf(v, 0.f);
                    pk[r] = f2bf(v);
                }
                *(short4v*)&out[((((size_t)b * CGO + cg) * PR + (h + 1)) * PC +
                                 (8 + wcol)) * 8 + sub] = pk;
            }
        }
    }
}

// ---------------------------------------------------------------------------
// conv1x1 (32 -> 9 logits) + softmax; reads bf16 8c-blocked padded t2.
// ---------------------------------------------------------------------------
__global__ void conv1x1_softmax_kernel(const short* __restrict__ t2,
                                       const float* __restrict__ w3,   // (9,32)
                                       const float* __restrict__ b3,
                                       float* __restrict__ kern) {     // (B,9,H,W)
    __shared__ float sw[9 * 32];
    __shared__ float sb[9];
    for (int i = threadIdx.x; i < 9 * 32; i += blockDim.x) sw[i] = w3[i];
    if (threadIdx.x < 9) sb[threadIdx.x] = b3[threadIdx.x];
    __syncthreads();

    int idx = blockIdx.x * blockDim.x + threadIdx.x;
    if (idx >= NPIX) return;
    int b = idx / HWSZ;
    int p = idx % HWSZ;
    int h = p / WW, w = p % WW;

    float v[32];
#pragma unroll
    for (int cg = 0; cg < 4; ++cg) {
        short8 pk = *(const short8*)
            &t2[((((size_t)b * 4 + cg) * PR + h + 1) * PC + (8 + w)) * 8];
#pragma unroll
        for (int j = 0; j < 8; ++j) v[cg * 8 + j] = bf2f(pk[j]);
    }

    float lg[9];
    float m = -1e30f;
#pragma unroll
    for (int t = 0; t < 9; ++t) {
        float s = sb[t];
#pragma unroll
        for (int c = 0; c < 32; ++c) s = fmaf(sw[t * 32 + c], v[c], s);
        lg[t] = s;
        m = fmaxf(m, s);
    }
    float sum = 0.f;
#pragma unroll
    for (int t = 0; t < 9; ++t) {
        lg[t] = __expf(lg[t] - m);
        sum += lg[t];
    }
    float inv = 1.f / sum;
#pragma unroll
    for (int t = 0; t < 9; ++t)
        kern[((size_t)(b * 9 + t)) * HWSZ + p] = lg[t] * inv;
}

// ---------------------------------------------------------------------------
// Adaptive 3x3 filter apply: fp32 x (exact) * fp32 kernel -> bf16 8c t3.
// ---------------------------------------------------------------------------
__global__ void deblur_kernel(const float* __restrict__ x,
                              const float* __restrict__ kern,
                              short* __restrict__ t3) {
    int idx = blockIdx.x * blockDim.x + threadIdx.x;
    if (idx >= BB * 16 * HWSZ) return;
    int w  = idx % WW;
    int h  = (idx / WW) % HH;
    int cg = (idx / HWSZ) % 16;
    int b  = idx / (HWSZ * 16);

    const float* kb = kern + (size_t)(b * 9) * HWSZ + h * WW + w;
    float kv[9];
#pragma unroll
    for (int t = 0; t < 9; ++t) kv[t] = kb[(size_t)t * HWSZ];

    const float* xb = x + (size_t)(b * CC + cg * 8) * HWSZ;
    float s[8] = {0.f, 0.f, 0.f, 0.f, 0.f, 0.f, 0.f, 0.f};
    int t = 0;
#pragma unroll
    for (int dy = 0; dy < 3; ++dy) {
#pragma unroll
        for (int dx = 0; dx < 3; ++dx) {
            int hh = h + dy - 1, ww2 = w + dx - 1;
            if ((unsigned)hh < (unsigned)HH && (unsigned)ww2 < (unsigned)WW) {
                const float* xp = xb + hh * WW + ww2;
#pragma unroll
                for (int j = 0; j < 8; ++j)
                    s[j] = fmaf(kv[t], xp[(size_t)j * HWSZ], s[j]);
            }
            ++t;
        }
    }
    short8 pk;
#pragma unroll
    for (int j = 0; j < 8; ++j) pk[j] = f2bf(s[j]);
    *(short8*)&t3[((((size_t)b * 16 + cg) * PR + h + 1) * PC + (8 + w)) * 8] = pk;
}

// ---------------------------------------------------------------------------
extern "C" void kernel_launch(void* const* d_in, const int* in_sizes, int n_in,
                              void* d_out, int out_size, void* d_ws, size_t ws_size,
                              hipStream_t stream) {
    const float* x   = (const float*)d_in[0];
    const float* w1  = (const float*)d_in[1];
    const float* b1  = (const float*)d_in[2];
    const float* w2  = (const float*)d_in[3];
    const float* b2  = (const float*)d_in[4];
    const float* w3  = (const float*)d_in[5];
    const float* b3  = (const float*)d_in[6];
    const float* f1  = (const float*)d_in[7];
    const float* fb1 = (const float*)d_in[8];
    const float* f2  = (const float*)d_in[9];
    const float* fb2 = (const float*)d_in[10];
    float* out = (float*)d_out;

    // workspace layout (bf16 activation buffers: [b][cg][PR][PC][8] units)
    const size_t ACT_SZ = (size_t)BB * 16 * PR * PC * 8;   // shorts, 128ch buffer
    short* xpad    = (short*)d_ws;
    short* regionA = xpad + ACT_SZ;       // t1 (64ch) then t3 (128ch)
    short* regionB = regionA + ACT_SZ;    // t2 (32ch) then t4 (128ch)
    float* kern    = (float*)(regionB + ACT_SZ);           // (B,9,H,W) fp32
    short* wp1     = (short*)(kern + (size_t)BB * 9 * HWSZ);
    short* wp2     = wp1 + 9 * 4 * 64 * 32;
    short* wpf1    = wp2 + 9 * 2 * 32 * 32;
    short* wpf2    = wpf1 + 9 * 4 * 128 * 32;

    short* t1 = regionA;
    short* t2 = regionB;
    short* t3 = regionA;   // overwrites t1 (dead)
    short* t4 = regionB;   // overwrites t2 (dead)

    // border zeroing + x conversion + weight prep
    {
        int nz = 3 * 64 * 800;
        zero_pads_kernel<<<(nz + 255) / 256, 256, 0, stream>>>(xpad, regionA, regionB);
        int nx = BB * 16 * HWSZ;
        x_prep_kernel<<<(nx + 255) / 256, 256, 0, stream>>>(x, xpad);
        int n1 = 9 * 4 * 64 * 32, n2 = 9 * 2 * 32 * 32, nf = 9 * 4 * 128 * 32;
        prep_w_kernel<<<(n1 + 255) / 256, 256, 0, stream>>>(w1, wp1, 128, 64, n1);
        prep_w_kernel<<<(n2 + 255) / 256, 256, 0, stream>>>(w2, wp2, 64, 32, n2);
        prep_w_kernel<<<(nf + 255) / 256, 256, 0, stream>>>(f1, wpf1, 128, 128, nf);
        prep_w_kernel<<<(nf + 255) / 256, 256, 0, stream>>>(f2, wpf2, 128, 128, nf);
    }

    // conv1: 128 -> 64, relu.  4 waves, each covers all 64 co (A shared)
    conv3x3_direct<128, 64, 4, 3, true, false>
        <<<dim3(HH, BB), 256, 0, stream>>>(xpad, wp1, b1, t1);
    // conv2: 64 -> 32, relu.   4 waves, each covers all 32 co
    conv3x3_direct<64, 32, 2, 3, true, false>
        <<<dim3(HH, BB), 256, 0, stream>>>(t1, wp2, b2, t2);
    // conv3 1x1 + softmax -> kern
    conv1x1_softmax_kernel<<<(NPIX + 255) / 256, 256, 0, stream>>>(t2, w3, b3, kern);
    // adaptive filter apply (exact fp32 x) -> bf16 t3
    {
        int nd = BB * 16 * HWSZ;
        deblur_kernel<<<(nd + 255) / 256, 256, 0, stream>>>(x, kern, t3);
    }
    // f1: 128 -> 128, relu.  4 waves, each covers all 128 co (WM=8, A shared)
    conv3x3_direct<128, 128, 8, 3, true, false>
        <<<dim3(HH, BB), 256, 0, stream>>>(t3, wpf1, fb1, t4);
    // f2: 128 -> 128, no relu -> final fp32 output
    conv3x3_direct<128, 128, 8, 3, false, true>
        <<<dim3(HH, BB), 256, 0, stream>>>(t4, wpf2, fb2, out);
}

// Round 7
// 495.200 us; speedup vs baseline: 1.0959x; 1.0959x over previous
//
#include <hip/hip_runtime.h>
#include <math.h>

// Problem constants (B, C, H, W) = (4, 128, 192, 192)
#define BB 4
#define CC 128
#define HH 192
#define WW 192
#define HWSZ (HH * WW)          // 36864
#define NPIX (BB * HWSZ)        // 147456
#define PR 194                  // padded rows (h = -1..192)
#define PC 208                  // padded col units (16B units; 128B-aligned rows)
// col unit for pixel w is (8 + w); zero borders at units 7 and 200.

typedef __attribute__((ext_vector_type(8))) short short8;
typedef __attribute__((ext_vector_type(4))) short short4v;
typedef __attribute__((ext_vector_type(4))) float float4v;

// fp32 -> bf16, round-to-nearest-even
__device__ __forceinline__ short f2bf(float f) {
    unsigned u = __float_as_uint(f);
    u += 0x7FFF + ((u >> 16) & 1);
    return (short)(u >> 16);
}
__device__ __forceinline__ float bf2f(short s) {
    return __uint_as_float(((unsigned)(unsigned short)s) << 16);
}

// ---------------------------------------------------------------------------
// Weight prep:  w[co][cin][ky][kx] fp32  ->  wp[ck][tap][co][ci] bf16
// ---------------------------------------------------------------------------
__global__ void prep_w_kernel(const float* __restrict__ w,
                              short* __restrict__ wp,
                              int CIN, int COUT, int total) {
    int idx = blockIdx.x * blockDim.x + threadIdx.x;
    if (idx >= total) return;
    int ci  = idx & 31;
    int rem = idx >> 5;
    int co  = rem % COUT;
    int r2  = rem / COUT;
    int tap = r2 % 9;
    int ck  = r2 / 9;
    int cin = ck * 32 + ci;
    wp[idx] = f2bf(w[(co * CIN + cin) * 9 + tap]);
}

// ---------------------------------------------------------------------------
// Zero the borders of the three padded bf16 activation buffers.
// ---------------------------------------------------------------------------
__global__ void zero_pads_kernel(short* __restrict__ p0,
                                 short* __restrict__ p1,
                                 short* __restrict__ p2) {
    int idx = blockIdx.x * blockDim.x + threadIdx.x;
    if (idx >= 3 * 64 * 800) return;
    int e   = idx % 800;
    int bc  = (idx / 800) % 64;
    int buf = idx / (800 * 64);
    short* base = (buf == 0) ? p0 : (buf == 1) ? p1 : p2;
    int row, col;
    if (e < 208)      { row = 0;   col = e; }
    else if (e < 416) { row = 193; col = e - 208; }
    else { int e2 = e - 416; row = 1 + (e2 >> 1); col = (e2 & 1) ? 200 : 7; }
    short8 z = {0, 0, 0, 0, 0, 0, 0, 0};
    *(short8*)&base[(((size_t)bc * PR + row) * PC + col) * 8] = z;
}

// ---------------------------------------------------------------------------
// x fp32 NCHW -> padded bf16 8c-blocked [b][cg][h+1][8+w][8]
// ---------------------------------------------------------------------------
__global__ void x_prep_kernel(const float* __restrict__ x,
                              short* __restrict__ xp) {
    int idx = blockIdx.x * blockDim.x + threadIdx.x;
    if (idx >= BB * 16 * HWSZ) return;
    int w  = idx % WW;
    int h  = (idx / WW) % HH;
    int cg = (idx / HWSZ) % 16;
    int b  = idx / (HWSZ * 16);
    const float* p = x + ((size_t)(b * CC + cg * 8) * HH + h) * WW + w;
    short8 pk;
#pragma unroll
    for (int j = 0; j < 8; ++j) pk[j] = f2bf(p[(size_t)j * HWSZ]);
    *(short8*)&xp[((((size_t)b * 16 + cg) * PR + h + 1) * PC + (8 + w)) * 8] = pk;
}

// ---------------------------------------------------------------------------
// Implicit-GEMM 3x3 conv, bf16 MFMA 16x16x32, fp32 accumulate.
// Block = 128 threads (2 waves), each wave a co-half (WAVES_M=2), both waves
// share one 64-px N-tile.  B: per-ck 12.7 KB LDS slab (global_load_lds DMA),
// taps read shifted ds_read_b128 (traffic on the LDS pipe).  A: from global
// (TCP pipe), depth-2 rotating prefetch (slot = tap%3; 9 = 0 mod 3).
// -> operand traffic split across both bandwidth paths, ~12 blocks/CU.
// ---------------------------------------------------------------------------
template <int CIN, int COUT, int COSPLIT, int WM, int WN, bool RELU, bool OUT_F32>
__global__ __launch_bounds__(128, 4)
void conv3x3_hyb(const short* __restrict__ in,
                 const short* __restrict__ wp,   // [ck][tap][co][32ci] bf16
                 const float* __restrict__ bias,
                 void* __restrict__ outv) {
    constexpr int CKN      = CIN / 32;
    constexpr int CG_IN    = CIN / 8;
    constexpr int CGO      = COUT / 8;
    constexpr int KT       = CKN * 9;
    constexpr int COUT_BLK = COUT / COSPLIT;
    constexpr int NTILE    = WN * 16;          // 64
    constexpr int SCOLS    = NTILE + 2;        // 66
    constexpr int UNITS    = 3 * 4 * SCOLS;    // 792 x 16B = 12,672 B
    static_assert(2 * WM * 16 == COUT_BLK, "M tiling");
    static_assert(NTILE == 64, "N tiling");

    __shared__ __align__(16) short s_x[UNITS * 8];

    const int tid  = threadIdx.x;
    const int px0  = blockIdx.x * NTILE;
    const int h    = blockIdx.y;
    const int z    = blockIdx.z;
    const int b    = z / COSPLIT;
    const int coB  = (z % COSPLIT) * COUT_BLK;
    const int lane = tid & 63;
    const int wv   = tid >> 6;               // wave = co-half 0..1
    const int ln15 = lane & 15;
    const int lg   = lane >> 4;              // k-subgroup 0..3 (8 cins each)

    float4v acc[WM][WN];
#pragma unroll
    for (int mi = 0; mi < WM; ++mi)
#pragma unroll
        for (int ni = 0; ni < WN; ++ni)
            acc[mi][ni] = (float4v){0.f, 0.f, 0.f, 0.f};

    short8 Aa[3][WM], Bf[2][WN];

    auto loadA = [&](int kt, short8* dst) {
        const int ck = kt / 9, tap = kt % 9;
#pragma unroll
        for (int mi = 0; mi < WM; ++mi) {
            int co = coB + (wv * WM + mi) * 16 + ln15;
            dst[mi] = *(const short8*)
                &wp[(((size_t)(ck * 9 + tap)) * COUT + co) * 32 + lg * 8];
        }
    };
    auto loadB = [&](int tap, short8* dst) {
        const int dy = tap / 3, dx = tap % 3;
#pragma unroll
        for (int ni = 0; ni < WN; ++ni) {
            int col = ni * 16 + ln15 + dx;             // 0..65
            dst[ni] = *(const short8*)&s_x[((dy * 4 + lg) * SCOLS + col) * 8];
        }
    };

    loadA(0, Aa[0]);
    loadA(1, Aa[1]);

    for (int ck = 0; ck < CKN; ++ck) {
        if (ck) __syncthreads();             // prior slab reads done
        // ---- stage 32-cin x 3-row x 66-col slab via DMA ----
#pragma unroll
        for (int u = 0; u < (UNITS + 127) / 128; ++u) {
            int i = tid + u * 128;
            if (i < UNITS) {
                int col = i % SCOLS;
                int rem = i / SCOLS;
                int g   = rem & 3;
                int r   = rem >> 2;
                const short* gp = in +
                    ((((size_t)b * CG_IN + ck * 4 + g) * PR + (h + r)) * PC +
                     (7 + px0 + col)) * 8;
                __builtin_amdgcn_global_load_lds(
                    (const __attribute__((address_space(1))) void*)gp,
                    (__attribute__((address_space(3))) void*)&s_x[i * 8], 16, 0, 0);
            }
        }
        __syncthreads();                     // DMA drained

        loadB(0, Bf[0]);
#pragma unroll
        for (int tap = 0; tap < 9; ++tap) {
            const int kt = ck * 9 + tap;
            if (kt + 2 < KT) loadA(kt + 2, Aa[(tap + 2) % 3]);   // 9%3==0
            if (tap < 8) loadB(tap + 1, Bf[(tap + 1) & 1]);
#pragma unroll
            for (int mi = 0; mi < WM; ++mi)
#pragma unroll
                for (int ni = 0; ni < WN; ++ni)
                    acc[mi][ni] = __builtin_amdgcn_mfma_f32_16x16x32_bf16(
                        Aa[tap % 3][mi], Bf[tap & 1][ni], acc[mi][ni], 0, 0, 0);
        }
    }

    // ---- epilogue: C layout col=lane&15 (pixel), row=lg*4+reg (cout) ----
    if (OUT_F32) {
        float* out = (float*)outv;
#pragma unroll
        for (int mi = 0; mi < WM; ++mi) {
            int co0 = coB + (wv * WM + mi) * 16 + lg * 4;
#pragma unroll
            for (int r = 0; r < 4; ++r) {
                int co = co0 + r;
                float bv = bias[co];
#pragma unroll
                for (int ni = 0; ni < WN; ++ni) {
                    int wcol = px0 + ni * 16 + ln15;
                    float v = acc[mi][ni][r] + bv;
                    if (RELU) v = fmaxf(v, 0.f);
                    out[((size_t)(b * COUT + co) * HH + h) * WW + wcol] = v;
                }
            }
        }
    } else {
        short* out = (short*)outv;
#pragma unroll
        for (int mi = 0; mi < WM; ++mi) {
            int co0 = coB + (wv * WM + mi) * 16 + lg * 4;  // 4 consecutive couts
            int cg  = co0 >> 3;
            int sub = co0 & 7;                             // 0 or 4
#pragma unroll
            for (int ni = 0; ni < WN; ++ni) {
                int wcol = px0 + ni * 16 + ln15;
                short4v pk;
#pragma unroll
                for (int r = 0; r < 4; ++r) {
                    float v = acc[mi][ni][r] + bias[co0 + r];
                    if (RELU) v = fmaxf(v, 0.f);
                    pk[r] = f2bf(v);
                }
                *(short4v*)&out[((((size_t)b * CGO + cg) * PR + (h + 1)) * PC +
                                 (8 + wcol)) * 8 + sub] = pk;
            }
        }
    }
}

// ---------------------------------------------------------------------------
// conv1x1 (32 -> 9 logits) + softmax; reads bf16 8c-blocked padded t2.
// ---------------------------------------------------------------------------
__global__ void conv1x1_softmax_kernel(const short* __restrict__ t2,
                                       const float* __restrict__ w3,   // (9,32)
                                       const float* __restrict__ b3,
                                       float* __restrict__ kern) {     // (B,9,H,W)
    __shared__ float sw[9 * 32];
    __shared__ float sb[9];
    for (int i = threadIdx.x; i < 9 * 32; i += blockDim.x) sw[i] = w3[i];
    if (threadIdx.x < 9) sb[threadIdx.x] = b3[threadIdx.x];
    __syncthreads();

    int idx = blockIdx.x * blockDim.x + threadIdx.x;
    if (idx >= NPIX) return;
    int b = idx / HWSZ;
    int p = idx % HWSZ;
    int h = p / WW, w = p % WW;

    float v[32];
#pragma unroll
    for (int cg = 0; cg < 4; ++cg) {
        short8 pk = *(const short8*)
            &t2[((((size_t)b * 4 + cg) * PR + h + 1) * PC + (8 + w)) * 8];
#pragma unroll
        for (int j = 0; j < 8; ++j) v[cg * 8 + j] = bf2f(pk[j]);
    }

    float lg[9];
    float m = -1e30f;
#pragma unroll
    for (int t = 0; t < 9; ++t) {
        float s = sb[t];
#pragma unroll
        for (int c = 0; c < 32; ++c) s = fmaf(sw[t * 32 + c], v[c], s);
        lg[t] = s;
        m = fmaxf(m, s);
    }
    float sum = 0.f;
#pragma unroll
    for (int t = 0; t < 9; ++t) {
        lg[t] = __expf(lg[t] - m);
        sum += lg[t];
    }
    float inv = 1.f / sum;
#pragma unroll
    for (int t = 0; t < 9; ++t)
        kern[((size_t)(b * 9 + t)) * HWSZ + p] = lg[t] * inv;
}

// ---------------------------------------------------------------------------
// Adaptive 3x3 filter apply: fp32 x (exact) * fp32 kernel -> bf16 8c t3.
// ---------------------------------------------------------------------------
__global__ void deblur_kernel(const float* __restrict__ x,
                              const float* __restrict__ kern,
                              short* __restrict__ t3) {
    int idx = blockIdx.x * blockDim.x + threadIdx.x;
    if (idx >= BB * 16 * HWSZ) return;
    int w  = idx % WW;
    int h  = (idx / WW) % HH;
    int cg = (idx / HWSZ) % 16;
    int b  = idx / (HWSZ * 16);

    const float* kb = kern + (size_t)(b * 9) * HWSZ + h * WW + w;
    float kv[9];
#pragma unroll
    for (int t = 0; t < 9; ++t) kv[t] = kb[(size_t)t * HWSZ];

    const float* xb = x + (size_t)(b * CC + cg * 8) * HWSZ;
    float s[8] = {0.f, 0.f, 0.f, 0.f, 0.f, 0.f, 0.f, 0.f};
    int t = 0;
#pragma unroll
    for (int dy = 0; dy < 3; ++dy) {
#pragma unroll
        for (int dx = 0; dx < 3; ++dx) {
            int hh = h + dy - 1, ww2 = w + dx - 1;
            if ((unsigned)hh < (unsigned)HH && (unsigned)ww2 < (unsigned)WW) {
                const float* xp = xb + hh * WW + ww2;
#pragma unroll
                for (int j = 0; j < 8; ++j)
                    s[j] = fmaf(kv[t], xp[(size_t)j * HWSZ], s[j]);
            }
            ++t;
        }
    }
    short8 pk;
#pragma unroll
    for (int j = 0; j < 8; ++j) pk[j] = f2bf(s[j]);
    *(short8*)&t3[((((size_t)b * 16 + cg) * PR + h + 1) * PC + (8 + w)) * 8] = pk;
}

// ---------------------------------------------------------------------------
extern "C" void kernel_launch(void* const* d_in, const int* in_sizes, int n_in,
                              void* d_out, int out_size, void* d_ws, size_t ws_size,
                              hipStream_t stream) {
    const float* x   = (const float*)d_in[0];
    const float* w1  = (const float*)d_in[1];
    const float* b1  = (const float*)d_in[2];
    const float* w2  = (const float*)d_in[3];
    const float* b2  = (const float*)d_in[4];
    const float* w3  = (const float*)d_in[5];
    const float* b3  = (const float*)d_in[6];
    const float* f1  = (const float*)d_in[7];
    const float* fb1 = (const float*)d_in[8];
    const float* f2  = (const float*)d_in[9];
    const float* fb2 = (const float*)d_in[10];
    float* out = (float*)d_out;

    // workspace layout (bf16 activation buffers: [b][cg][PR][PC][8] units)
    const size_t ACT_SZ = (size_t)BB * 16 * PR * PC * 8;   // shorts, 128ch buffer
    short* xpad    = (short*)d_ws;
    short* regionA = xpad + ACT_SZ;       // t1 (64ch) then t3 (128ch)
    short* regionB = regionA + ACT_SZ;    // t2 (32ch) then t4 (128ch)
    float* kern    = (float*)(regionB + ACT_SZ);           // (B,9,H,W) fp32
    short* wp1     = (short*)(kern + (size_t)BB * 9 * HWSZ);
    short* wp2     = wp1 + 9 * 4 * 64 * 32;
    short* wpf1    = wp2 + 9 * 2 * 32 * 32;
    short* wpf2    = wpf1 + 9 * 4 * 128 * 32;

    short* t1 = regionA;
    short* t2 = regionB;
    short* t3 = regionA;   // overwrites t1 (dead)
    short* t4 = regionB;   // overwrites t2 (dead)

    // border zeroing + x conversion + weight prep
    {
        int nz = 3 * 64 * 800;
        zero_pads_kernel<<<(nz + 255) / 256, 256, 0, stream>>>(xpad, regionA, regionB);
        int nx = BB * 16 * HWSZ;
        x_prep_kernel<<<(nx + 255) / 256, 256, 0, stream>>>(x, xpad);
        int n1 = 9 * 4 * 64 * 32, n2 = 9 * 2 * 32 * 32, nf = 9 * 4 * 128 * 32;
        prep_w_kernel<<<(n1 + 255) / 256, 256, 0, stream>>>(w1, wp1, 128, 64, n1);
        prep_w_kernel<<<(n2 + 255) / 256, 256, 0, stream>>>(w2, wp2, 64, 32, n2);
        prep_w_kernel<<<(nf + 255) / 256, 256, 0, stream>>>(f1, wpf1, 128, 128, nf);
        prep_w_kernel<<<(nf + 255) / 256, 256, 0, stream>>>(f2, wpf2, 128, 128, nf);
    }

    // conv1: 128 -> 64, relu.  2 waves x (WM=2), 64 px tiles -> 2304 blocks
    conv3x3_hyb<128, 64, 1, 2, 4, true, false>
        <<<dim3(3, HH, BB), 128, 0, stream>>>(xpad, wp1, b1, t1);
    // conv2: 64 -> 32, relu.   WM=1 -> 2304 blocks
    conv3x3_hyb<64, 32, 1, 1, 4, true, false>
        <<<dim3(3, HH, BB), 128, 0, stream>>>(t1, wp2, b2, t2);
    // conv3 1x1 + softmax -> kern
    conv1x1_softmax_kernel<<<(NPIX + 255) / 256, 256, 0, stream>>>(t2, w3, b3, kern);
    // adaptive filter apply (exact fp32 x) -> bf16 t3
    {
        int nd = BB * 16 * HWSZ;
        deblur_kernel<<<(nd + 255) / 256, 256, 0, stream>>>(x, kern, t3);
    }
    // f1: 128 -> 128, relu.  co-split 2 -> 4608 blocks
    conv3x3_hyb<128, 128, 2, 2, 4, true, false>
        <<<dim3(3, HH, BB * 2), 128, 0, stream>>>(t3, wpf1, fb1, t4);
    // f2: 128 -> 128, no relu -> final fp32 output
    conv3x3_hyb<128, 128, 2, 2, 4, false, true>
        <<<dim3(3, HH, BB * 2), 128, 0, stream>>>(t4, wpf2, fb2, out);
}